// Round 1
// baseline (113.409 us; speedup 1.0000x reference)
//
#include <hip/hip_runtime.h>

#define TSD 512      // TS (feature dim)
#define SRC 256
#define TGT 256
#define NB  4        // batch
#define TB  2        // target rows per attn block

// ---------------------------------------------------------------------------
// Projection GEMM: OUT[r][o] = sum_d X[r][d] * W[o][wofs+d] (+ bias for z=1)
// X: (1024, 512) row-major, W: (512, 1024) row-major, OUT: (1024, 512)
// 64x64 tiles, 16x16 threads, 4x4 micro-tile, BK=16.
// ---------------------------------------------------------------------------
__global__ __launch_bounds__(256) void proj_kernel(
    const float* __restrict__ hid, const float* __restrict__ enc,
    const float* __restrict__ W, const float* __restrict__ bias,
    float* __restrict__ hp, float* __restrict__ ep)
{
    const int z = blockIdx.z;
    const float* __restrict__ X = z ? enc : hid;
    float* __restrict__ OUT = z ? ep : hp;
    const int wofs = z ? TSD : 0;

    __shared__ float Xs[16][68];   // [k][m], pad 68 (16B-aligned rows, conflict-lite)
    __shared__ float Ws[16][68];   // [k][n]

    const int tx = threadIdx.x, ty = threadIdx.y;
    const int tid = ty * 16 + tx;
    const int o0 = blockIdx.x * 64;
    const int r0 = blockIdx.y * 64;

    const int m  = tid >> 2;        // 0..63
    const int kq = (tid & 3) * 4;   // 0,4,8,12

    float acc[4][4] = {};

    for (int k0 = 0; k0 < TSD; k0 += 16) {
        __syncthreads();
        float4 av = *reinterpret_cast<const float4*>(&X[(r0 + m) * TSD + k0 + kq]);
        float4 wv = *reinterpret_cast<const float4*>(&W[(o0 + m) * (2 * TSD) + wofs + k0 + kq]);
        Xs[kq + 0][m] = av.x; Xs[kq + 1][m] = av.y; Xs[kq + 2][m] = av.z; Xs[kq + 3][m] = av.w;
        Ws[kq + 0][m] = wv.x; Ws[kq + 1][m] = wv.y; Ws[kq + 2][m] = wv.z; Ws[kq + 3][m] = wv.w;
        __syncthreads();
        #pragma unroll
        for (int k = 0; k < 16; ++k) {
            float4 a = *reinterpret_cast<const float4*>(&Xs[k][ty * 4]);
            float4 bb = *reinterpret_cast<const float4*>(&Ws[k][tx * 4]);
            float ar[4] = {a.x, a.y, a.z, a.w};
            float br[4] = {bb.x, bb.y, bb.z, bb.w};
            #pragma unroll
            for (int i = 0; i < 4; ++i)
                #pragma unroll
                for (int j = 0; j < 4; ++j)
                    acc[i][j] = fmaf(ar[i], br[j], acc[i][j]);
        }
    }

    #pragma unroll
    for (int i = 0; i < 4; ++i) {
        const int r = r0 + ty * 4 + i;
        float4 o;
        float bb0 = 0.f, bb1 = 0.f, bb2 = 0.f, bb3 = 0.f;
        if (z) {
            bb0 = bias[o0 + tx * 4 + 0];
            bb1 = bias[o0 + tx * 4 + 1];
            bb2 = bias[o0 + tx * 4 + 2];
            bb3 = bias[o0 + tx * 4 + 3];
        }
        o.x = acc[i][0] + bb0; o.y = acc[i][1] + bb1;
        o.z = acc[i][2] + bb2; o.w = acc[i][3] + bb3;
        *reinterpret_cast<float4*>(&OUT[r * TSD + o0 + tx * 4]) = o;
    }
}

// ---------------------------------------------------------------------------
// Block reductions (256 threads = 4 waves of 64)
// ---------------------------------------------------------------------------
__device__ __forceinline__ float wave_sum(float v) {
    #pragma unroll
    for (int off = 1; off < 64; off <<= 1) v += __shfl_xor(v, off, 64);
    return v;
}
__device__ __forceinline__ float wave_max(float v) {
    #pragma unroll
    for (int off = 1; off < 64; off <<= 1) v = fmaxf(v, __shfl_xor(v, off, 64));
    return v;
}
__device__ __forceinline__ float block_sum(float v, float* red) {
    v = wave_sum(v);
    __syncthreads();
    if ((threadIdx.x & 63) == 0) red[threadIdx.x >> 6] = v;
    __syncthreads();
    return red[0] + red[1] + red[2] + red[3];
}
__device__ __forceinline__ float block_max(float v, float* red) {
    v = wave_max(v);
    __syncthreads();
    if ((threadIdx.x & 63) == 0) red[threadIdx.x >> 6] = v;
    __syncthreads();
    return fmaxf(fmaxf(red[0], red[1]), fmaxf(red[2], red[3]));
}

// ---------------------------------------------------------------------------
// Fused score + softmax + context. One block per TB target rows of one batch.
// score[t][s] = sum_o v[o]*tanh(hp[t][o] + ep[s][o])
//   with  sum v*tanh(x) = sum(v) - 2*sum(v / (exp(2x)+1))
// ---------------------------------------------------------------------------
__global__ __launch_bounds__(256) void attn_kernel(
    const float* __restrict__ hp, const float* __restrict__ ep,
    const float* __restrict__ enc, const int* __restrict__ mask,
    const float* __restrict__ v,
    float* __restrict__ ctx_out, float* __restrict__ probs_out)
{
    __shared__ float eps[SRC][65];      // ep chunk: [s][o], pad 65 -> bank (s+o)%32
    __shared__ float hp_s[TB][TSD];
    __shared__ float v_s[TSD];
    __shared__ float p_lds[TB][SRC];
    __shared__ float red[4];

    const int tid = threadIdx.x;
    const int b = blockIdx.y;
    const int t0 = blockIdx.x * TB;
    const int s = tid;

    // stage hp rows and v; accumulate partial sum(v)
    for (int i = tid; i < TB * TSD; i += 256)
        hp_s[i / TSD][i % TSD] = hp[(b * TGT + t0 + i / TSD) * TSD + (i % TSD)];
    float sv_part = 0.f;
    for (int i = tid; i < TSD; i += 256) { float vv = v[i]; v_s[i] = vv; sv_part += vv; }
    const float sumv = block_sum(sv_part, red);

    float acc0 = 0.f, acc1 = 0.f;
    const int col = tid & 63, rr0 = tid >> 6;
    const float C2 = 2.0f;

    for (int o0 = 0; o0 < TSD; o0 += 64) {
        __syncthreads();
        #pragma unroll 4
        for (int i = 0; i < 64; ++i) {
            const int r = rr0 + 4 * i;
            eps[r][col] = ep[(b * SRC + r) * TSD + o0 + col];
        }
        __syncthreads();
        #pragma unroll 8
        for (int oi = 0; oi < 64; ++oi) {
            const float e  = eps[s][oi];
            const float vv = v_s[o0 + oi];
            const float x0 = hp_s[0][o0 + oi] + e;
            const float x1 = hp_s[1][o0 + oi] + e;
            const float z0 = __expf(C2 * x0);
            const float z1 = __expf(C2 * x1);
            acc0 = fmaf(vv, __builtin_amdgcn_rcpf(z0 + 1.f), acc0);
            acc1 = fmaf(vv, __builtin_amdgcn_rcpf(z1 + 1.f), acc1);
        }
    }

    float score[TB] = { sumv - 2.f * acc0, sumv - 2.f * acc1 };
    const float msk = (float)mask[b * SRC + s];

    #pragma unroll
    for (int tt = 0; tt < TB; ++tt) {
        const float sc = score[tt];
        const float bmax = block_max(sc, red);
        const float e = __expf(sc - bmax);
        const float sumE = block_sum(e, red);
        const float q = e / sumE;              // full softmax (reference order)
        const float mq = q * msk;              // mask
        const float summq = block_sum(mq, red);
        const float p = mq / (summq + 1e-12f); // renormalize
        p_lds[tt][s] = p;
        probs_out[(b * TGT + t0 + tt) * SRC + s] = p;
    }
    __syncthreads();

    // context: each thread owns columns d = tid and tid+256
    float c00 = 0.f, c01 = 0.f, c10 = 0.f, c11 = 0.f;
    for (int s2 = 0; s2 < SRC; ++s2) {
        const float e0 = enc[(b * SRC + s2) * TSD + tid];
        const float e1 = enc[(b * SRC + s2) * TSD + tid + 256];
        const float p0 = p_lds[0][s2];
        const float p1 = p_lds[1][s2];
        c00 = fmaf(p0, e0, c00); c01 = fmaf(p0, e1, c01);
        c10 = fmaf(p1, e0, c10); c11 = fmaf(p1, e1, c11);
    }
    ctx_out[(b * TGT + t0 + 0) * TSD + tid]       = c00;
    ctx_out[(b * TGT + t0 + 0) * TSD + tid + 256] = c01;
    ctx_out[(b * TGT + t0 + 1) * TSD + tid]       = c10;
    ctx_out[(b * TGT + t0 + 1) * TSD + tid + 256] = c11;
}

extern "C" void kernel_launch(void* const* d_in, const int* in_sizes, int n_in,
                              void* d_out, int out_size, void* d_ws, size_t ws_size,
                              hipStream_t stream) {
    const float* hid  = (const float*)d_in[0];   // (4,256,512)
    const float* enc  = (const float*)d_in[1];   // (4,256,512)
    const int*   mask = (const int*)  d_in[2];   // (4,256)
    const float* W    = (const float*)d_in[3];   // (512,1024)
    const float* bias = (const float*)d_in[4];   // (512,)
    const float* v    = (const float*)d_in[5];   // (512,)

    float* out   = (float*)d_out;
    float* ctx   = out;                       // 4*256*512
    float* probs = out + NB * TGT * TSD;      // 4*256*256

    float* hp = (float*)d_ws;                 // 1024*512
    float* ep = hp + NB * TGT * TSD;          // 1024*512

    dim3 pb(16, 16);
    dim3 pg(TSD / 64, (NB * TGT) / 64, 2);
    proj_kernel<<<pg, pb, 0, stream>>>(hid, enc, W, bias, hp, ep);

    dim3 ag(TGT / TB, NB);
    attn_kernel<<<ag, 256, 0, stream>>>(hp, ep, enc, mask, v, ctx, probs);
}

// Round 2
// 94.871 us; speedup vs baseline: 1.1954x; 1.1954x over previous
//
#include <hip/hip_runtime.h>

#define TSD 512      // TS (feature dim)
#define SRC 256
#define TGT 256
#define NB  4        // batch
#define KSCALE 2.885390081777927f   // 2*log2(e): exp2(K*x) == exp(2x)

// ---------------------------------------------------------------------------
// Projection GEMM: 64x64 tiles, 16x16 threads, 4x4 micro-tile, BK=16.
// z=0: hp'[r][o]   = K * (hid . Wh)[r][o]                  (row-major [r][o])
// z=1: epT[b][o][s] = K * ((enc . We)[r][o] + bias[o])     (TRANSPOSED [o][s])
// ---------------------------------------------------------------------------
__global__ __launch_bounds__(256) void proj_kernel(
    const float* __restrict__ hid, const float* __restrict__ enc,
    const float* __restrict__ W, const float* __restrict__ bias,
    float* __restrict__ hp, float* __restrict__ epT)
{
    const int z = blockIdx.z;
    const float* __restrict__ X = z ? enc : hid;
    const int wofs = z ? TSD : 0;

    __shared__ float Xs[16][68];   // [k][m]
    __shared__ float Ws[16][68];   // [k][n]

    const int tx = threadIdx.x, ty = threadIdx.y;
    const int tid = ty * 16 + tx;
    const int o0 = blockIdx.x * 64;
    const int r0 = blockIdx.y * 64;

    const int m  = tid >> 2;        // 0..63
    const int kq = (tid & 3) * 4;   // 0,4,8,12

    float acc[4][4] = {};

    for (int k0 = 0; k0 < TSD; k0 += 16) {
        __syncthreads();
        float4 av = *reinterpret_cast<const float4*>(&X[(r0 + m) * TSD + k0 + kq]);
        float4 wv = *reinterpret_cast<const float4*>(&W[(o0 + m) * (2 * TSD) + wofs + k0 + kq]);
        Xs[kq + 0][m] = av.x; Xs[kq + 1][m] = av.y; Xs[kq + 2][m] = av.z; Xs[kq + 3][m] = av.w;
        Ws[kq + 0][m] = wv.x; Ws[kq + 1][m] = wv.y; Ws[kq + 2][m] = wv.z; Ws[kq + 3][m] = wv.w;
        __syncthreads();
        #pragma unroll
        for (int k = 0; k < 16; ++k) {
            float4 a  = *reinterpret_cast<const float4*>(&Xs[k][ty * 4]);
            float4 bb = *reinterpret_cast<const float4*>(&Ws[k][tx * 4]);
            float ar[4] = {a.x, a.y, a.z, a.w};
            float br[4] = {bb.x, bb.y, bb.z, bb.w};
            #pragma unroll
            for (int i = 0; i < 4; ++i)
                #pragma unroll
                for (int j = 0; j < 4; ++j)
                    acc[i][j] = fmaf(ar[i], br[j], acc[i][j]);
        }
    }

    if (z) {
        const int bb_ = r0 >> 8;              // batch of this row-tile (64 | 256)
        const int sl  = (r0 & 255) + ty * 4;  // s within batch
        #pragma unroll
        for (int j = 0; j < 4; ++j) {
            const int o = o0 + tx * 4 + j;
            const float bj = bias[o];
            float4 val;
            val.x = (acc[0][j] + bj) * KSCALE;
            val.y = (acc[1][j] + bj) * KSCALE;
            val.z = (acc[2][j] + bj) * KSCALE;
            val.w = (acc[3][j] + bj) * KSCALE;
            *reinterpret_cast<float4*>(&epT[((size_t)bb_ * TSD + o) * SRC + sl]) = val;
        }
    } else {
        #pragma unroll
        for (int i = 0; i < 4; ++i) {
            const int r = r0 + ty * 4 + i;
            float4 o4;
            o4.x = acc[i][0] * KSCALE; o4.y = acc[i][1] * KSCALE;
            o4.z = acc[i][2] * KSCALE; o4.w = acc[i][3] * KSCALE;
            *reinterpret_cast<float4*>(&hp[r * TSD + o0 + tx * 4]) = o4;
        }
    }
}

// ---------------------------------------------------------------------------
// Reductions for 512-thread block split into two 256-thread halves (4 waves ea)
// ---------------------------------------------------------------------------
__device__ __forceinline__ float wave_red_sum(float v) {
    #pragma unroll
    for (int off = 1; off < 64; off <<= 1) v += __shfl_xor(v, off, 64);
    return v;
}
__device__ __forceinline__ float wave_red_max(float v) {
    #pragma unroll
    for (int off = 1; off < 64; off <<= 1) v = fmaxf(v, __shfl_xor(v, off, 64));
    return v;
}
__device__ __forceinline__ float half_sum(float val, float* red, int tid) {
    float w = wave_red_sum(val);
    __syncthreads();
    if ((tid & 63) == 0) red[tid >> 6] = w;
    __syncthreads();
    const int base = (tid >> 8) << 2;
    return red[base] + red[base + 1] + red[base + 2] + red[base + 3];
}
__device__ __forceinline__ float half_max(float val, float* red, int tid) {
    float w = wave_red_max(val);
    __syncthreads();
    if ((tid & 63) == 0) red[tid >> 6] = w;
    __syncthreads();
    const int base = (tid >> 8) << 2;
    return fmaxf(fmaxf(red[base], red[base + 1]), fmaxf(red[base + 2], red[base + 3]));
}
__device__ __forceinline__ float block_sum512(float val, float* red, int tid) {
    float w = wave_red_sum(val);
    __syncthreads();
    if ((tid & 63) == 0) red[tid >> 6] = w;
    __syncthreads();
    float r = 0.f;
    #pragma unroll
    for (int i = 0; i < 8; ++i) r += red[i];
    return r;
}

// ---------------------------------------------------------------------------
// Fused score + softmax + context. Block = 512 threads = (t in 0..1) x (s in 0..255).
// score[t][s] = sumv - 2 * sum_o v[o] / (exp2(hp'[t][o] + epT[o][s]) + 1)
// ---------------------------------------------------------------------------
__global__ __launch_bounds__(512, 4) void attn_kernel(
    const float* __restrict__ hp, const float* __restrict__ epT,
    const float* __restrict__ enc, const int* __restrict__ mask,
    const float* __restrict__ v,
    float* __restrict__ ctx_out, float* __restrict__ probs_out)
{
    __shared__ float p_lds[2][SRC];
    __shared__ float red[8];

    const int tid = threadIdx.x;
    const int hid = __builtin_amdgcn_readfirstlane(tid >> 8);  // wave-uniform half id
    const int s = tid & 255;
    const int b = blockIdx.y;
    const int t0 = blockIdx.x * 2;
    const int t = t0 + hid;

    // sum(v): all 512 threads each grab one element
    const float sumv = block_sum512(v[tid], red, tid);

    const float* __restrict__ hprow = hp + ((size_t)(b * TGT + t)) * TSD;  // uniform per wave
    const float* __restrict__ epb   = epT + (size_t)b * TSD * SRC;

    float acc = 0.f;
    #pragma unroll 8
    for (int o = 0; o < TSD; ++o) {
        const float e = epb[o * SRC + s];                  // coalesced, L2-hot
        const float x = hprow[o] + e;                      // hprow[o], v[o]: scalar loads
        const float z = __builtin_amdgcn_exp2f(x);         // = exp(2*(h+e+b))
        acc = fmaf(v[o], __builtin_amdgcn_rcpf(z + 1.f), acc);
    }
    const float score = sumv - 2.f * acc;

    // softmax (full) -> mask -> renormalize, per half-block row
    const float bmax = half_max(score, red, tid);
    const float eE = __expf(score - bmax);
    const float sE = half_sum(eE, red, tid);
    const float q = eE / sE;
    const float mq = q * (float)mask[b * SRC + s];
    const float smq = half_sum(mq, red, tid);
    const float p = mq / (smq + 1e-12f);
    p_lds[hid][s] = p;
    probs_out[((size_t)(b * TGT + t)) * SRC + s] = p;
    __syncthreads();

    // context: thread owns output column d = tid (512 cols), both t rows
    float c0 = 0.f, c1 = 0.f;
    const float* __restrict__ encb = enc + (size_t)b * SRC * TSD;
    #pragma unroll 4
    for (int s2 = 0; s2 < SRC; ++s2) {
        const float ev = encb[s2 * TSD + tid];
        c0 = fmaf(p_lds[0][s2], ev, c0);
        c1 = fmaf(p_lds[1][s2], ev, c1);
    }
    ctx_out[((size_t)(b * TGT + t0 + 0)) * TSD + tid] = c0;
    ctx_out[((size_t)(b * TGT + t0 + 1)) * TSD + tid] = c1;
}

extern "C" void kernel_launch(void* const* d_in, const int* in_sizes, int n_in,
                              void* d_out, int out_size, void* d_ws, size_t ws_size,
                              hipStream_t stream) {
    const float* hid  = (const float*)d_in[0];   // (4,256,512)
    const float* enc  = (const float*)d_in[1];   // (4,256,512)
    const int*   mask = (const int*)  d_in[2];   // (4,256)
    const float* W    = (const float*)d_in[3];   // (512,1024)
    const float* bias = (const float*)d_in[4];   // (512,)
    const float* v    = (const float*)d_in[5];   // (512,)

    float* out   = (float*)d_out;
    float* ctx   = out;                       // 4*256*512
    float* probs = out + NB * TGT * TSD;      // 4*256*256

    float* hp  = (float*)d_ws;                // 1024*512 (K-scaled)
    float* epT = hp + NB * TGT * TSD;         // 4*512*256 (K-scaled, +bias, transposed)

    dim3 pb(16, 16);
    dim3 pg(TSD / 64, (NB * TGT) / 64, 2);
    proj_kernel<<<pg, pb, 0, stream>>>(hid, enc, W, bias, hp, epT);

    dim3 ag(TGT / 2, NB);
    attn_kernel<<<ag, 512, 0, stream>>>(hp, epT, enc, mask, v, ctx, probs);
}